// Round 7
// baseline (526.822 us; speedup 1.0000x reference)
//
#include <hip/hip_runtime.h>

typedef float f32x4 __attribute__((ext_vector_type(4)));
typedef short s16x8 __attribute__((ext_vector_type(8)));

#define ECAP 36864   // padded per-bucket edge capacity (mean 32768, +22 sigma)

__device__ __forceinline__ ushort f2bf(float f) {
  uint u = __builtin_bit_cast(uint, f);
  u += 0x7fffu + ((u >> 16) & 1u);
  return (ushort)(u >> 16);
}
__device__ __forceinline__ float bfu_lo(uint u) { return __builtin_bit_cast(float, u << 16); }
__device__ __forceinline__ float bfu_hi(uint u) { return __builtin_bit_cast(float, u & 0xffff0000u); }

// ---------------- reformat 8 weight matrices into MFMA B-fragment order ----------------
// Wf[m][(nt*4+ks)*64 + lane][i] = bf16( W_m[ks*32 + (lane>>4)*8 + i][nt*16 + (lane&15)] )
__global__ void k_prepw(const float* __restrict__ Wp1, const float* __restrict__ Wp2,
                        const float* __restrict__ W1s, const float* __restrict__ W2s,
                        ushort* __restrict__ Wf) {
  int t = blockIdx.x * blockDim.x + threadIdx.x;
  if (t >= 8 * 2048) return;
  int m = t >> 11;
  int r = t & 2047;
  int lane = r & 63;
  int ksnt = r >> 6;
  int ks = ksnt & 3;
  int nt = ksnt >> 2;
  const float* src = (m == 0) ? Wp1 : (m == 1) ? Wp2
                     : (m < 5) ? (W1s + (size_t)(m - 2) * 16384)
                               : (W2s + (size_t)(m - 5) * 16384);
  ushort* dst = Wf + (size_t)m * 16384 + (size_t)r * 8;
  int c = nt * 16 + (lane & 15);
  int kbase = ks * 32 + (lane >> 4) * 8;
  for (int i = 0; i < 8; ++i) dst[i] = f2bf(src[(size_t)(kbase + i) * 128 + c]);
}

// ---------------- bucket append cursors ----------------
__global__ void k_binit(int* __restrict__ bcur, int nbk) {
  int b = threadIdx.x;
  if (b <= nbk) bcur[b] = b * ECAP;
}

// ---------------- LDS-staged multi-split: partition edges into dst-range buckets ---------
#define PNBK 64
#define PCAP 80
#define PEPB 2048
__global__ __launch_bounds__(256)
void k_part(const int* __restrict__ src, const int* __restrict__ dst,
            int* __restrict__ bcur, uint2* __restrict__ ebuf, int E) {
  __shared__ uint2 stage[PNBK][PCAP];
  __shared__ int lcnt[PNBK];
  int tid = threadIdx.x;
  if (tid < PNBK) lcnt[tid] = 0;
  __syncthreads();
  int e0 = blockIdx.x * PEPB;
  for (int r = 0; r < PEPB / 256; ++r) {
    int e = e0 + r * 256 + tid;
    if (e < E) {
      int d = dst[e], s = src[e];
      int b = d >> 11;
      int pos = atomicAdd(&lcnt[b], 1);
      uint2 pr; pr.x = (uint)s; pr.y = (uint)d;
      if (pos < PCAP) {
        stage[b][pos] = pr;
      } else {  // overflow fallback (correct for any data)
        int p = atomicAdd(&bcur[b], 1);
        ebuf[p] = pr;
      }
    }
    if (r == 3 || r == PEPB / 256 - 1) {
      __syncthreads();
      if (tid < PNBK) {
        int c = lcnt[tid];
        if (c > PCAP) c = PCAP;
        if (c > 0) {
          int base = atomicAdd(&bcur[tid], c);
          for (int i = 0; i < c; ++i) ebuf[base + i] = stage[tid][i];
          lcnt[tid] = 0;
        }
      }
      __syncthreads();
    }
  }
}

// ---------------- per-bucket LDS counting sort ----------------
__global__ __launch_bounds__(1024)
void k_sort(const uint2* __restrict__ ebuf, const int* __restrict__ bcur,
            int* __restrict__ rowbeg, int* __restrict__ rowend,
            int* __restrict__ csr, int N) {
  __shared__ int lcnt[2048];
  __shared__ int loff[2048];
  __shared__ int wsum[16];
  const int b = blockIdx.x;
  const int tid = threadIdx.x;
  const int lane = tid & 63, w = tid >> 6;
  const int base_e = b * ECAP;
  const int node0 = b << 11;
  const int ecnt = bcur[b] - base_e;

  lcnt[tid] = 0; lcnt[tid + 1024] = 0;
  __syncthreads();
  for (int i = tid; i < ecnt; i += 1024) {
    int d = (int)ebuf[base_e + i].y;
    atomicAdd(&lcnt[d - node0], 1);
  }
  __syncthreads();
  int v0 = lcnt[2 * tid], v1 = lcnt[2 * tid + 1];
  int s = v0 + v1;
  for (int off = 1; off < 64; off <<= 1) {
    int t = __shfl_up(s, off);
    if (lane >= off) s += t;
  }
  if (lane == 63) wsum[w] = s;
  __syncthreads();
  if (w == 0 && lane < 16) {
    int x = wsum[lane];
    int sx = x;
    for (int off = 1; off < 16; off <<= 1) {
      int t = __shfl_up(sx, off);
      if (lane >= off) sx += t;
    }
    wsum[lane] = sx - x;
  }
  __syncthreads();
  int excl = wsum[w] + (s - v0 - v1);
  loff[2 * tid] = excl;
  loff[2 * tid + 1] = excl + v0;
  __syncthreads();
  for (int i = tid; i < 2048; i += 1024) {
    int g = node0 + i;
    if (g < N) {
      int rb = base_e + loff[i];
      rowbeg[g] = rb;
      rowend[g] = rb + lcnt[i];
    }
    lcnt[i] = 0;
  }
  __syncthreads();
  for (int i = tid; i < ecnt; i += 1024) {
    uint2 p = ebuf[base_e + i];
    int dloc = (int)p.y - node0;
    int pos = base_e + loff[dloc] + atomicAdd(&lcnt[dloc], 1);
    csr[pos] = (int)p.x;
  }
}

// ---------------- column-chunked aggregation: z = (1+eps)*h + sum h[src] ----------------
// 4 column-chunks of 32 features (64 B). chunk = (blockIdx&7)>>1 so each XCD pair only
// gathers from its quarter of the h-table (6.4 MB, L2-resident).
// Wave = 4 x 16-lane sub-waves, one node each; 64 B per neighbor gather.
__global__ void k_agg(const ushort* __restrict__ H, const int* __restrict__ rowbeg,
                      const int* __restrict__ rowend, const int* __restrict__ csr,
                      ushort* __restrict__ Z, const float* __restrict__ eps,
                      int layer, int n_nodes) {
  const int bid = blockIdx.x;
  const int c = (bid & 7) >> 1;                    // column chunk 0..3
  const int nb = ((bid >> 3) << 1) | (bid & 1);    // node-block index
  const int wid = threadIdx.x >> 6;
  const int lane = threadIdx.x & 63;
  const int sub = lane >> 4, l16 = lane & 15;
  const int n = nb * 16 + wid * 4 + sub;
  if (n >= n_nodes) return;
  const float e = 1.0f + eps[layer];
  const uint* hc = (const uint*)H + c * 16;        // chunk column offset
  uint u = hc[(size_t)n * 64 + l16];
  float a0 = bfu_lo(u) * e, a1 = bfu_hi(u) * e;
  const int s0 = rowbeg[n], s1 = rowend[n];
  for (int base = s0; base < s1; base += 16) {
    int cnt = s1 - base;
    if (cnt > 16) cnt = 16;
    int idx = (l16 < cnt) ? csr[base + l16] : 0;
    const int sb = sub << 4;
    int j = 0;
    for (; j + 4 <= cnt; j += 4) {
      int i0 = __shfl(idx, sb + j);
      int i1 = __shfl(idx, sb + j + 1);
      int i2 = __shfl(idx, sb + j + 2);
      int i3 = __shfl(idx, sb + j + 3);
      uint u0 = hc[(size_t)i0 * 64 + l16];
      uint u1 = hc[(size_t)i1 * 64 + l16];
      uint u2 = hc[(size_t)i2 * 64 + l16];
      uint u3 = hc[(size_t)i3 * 64 + l16];
      a0 += bfu_lo(u0); a1 += bfu_hi(u0);
      a0 += bfu_lo(u1); a1 += bfu_hi(u1);
      a0 += bfu_lo(u2); a1 += bfu_hi(u2);
      a0 += bfu_lo(u3); a1 += bfu_hi(u3);
    }
    for (; j < cnt; ++j) {
      int si = __shfl(idx, sb + j);
      uint uu = hc[(size_t)si * 64 + l16];
      a0 += bfu_lo(uu); a1 += bfu_hi(uu);
    }
  }
  ((uint*)Z)[(size_t)n * 64 + c * 16 + l16] = (uint)f2bf(a0) | ((uint)f2bf(a1) << 16);
}

// ---------------- shared GEMM-from-LDS helper (swizzled 16x128 bf16 tile) ----------------
// tile element (row, col) bf16 stored at byte (row*256 + col*2) ^ ((row&7)<<4)
__device__ __forceinline__ void gemm_lds(const uint* T, const s16x8* wf, f32x4 acc[8], int lane) {
  const int row = lane & 15, hi = lane >> 4;
#pragma unroll
  for (int ks = 0; ks < 4; ++ks) {
    int ub = row * 64 + ((ks * 16 + hi * 4) ^ ((row & 7) << 2));
    s16x8 af = *(const s16x8*)(T + ub);
#pragma unroll
    for (int nt = 0; nt < 8; ++nt)
      acc[nt] = __builtin_amdgcn_mfma_f32_16x16x32_bf16(af, wf[(nt * 4 + ks) * 64 + lane], acc[nt], 0, 0, 0);
  }
}

// ---------------- fused layer MLP: h' = relu(z@W1+b1)@W2+b2, + per-graph pool ----------
__global__ __launch_bounds__(256, 4)
void k_mlp(const ushort* __restrict__ Z, const ushort* __restrict__ Wf1,
           const ushort* __restrict__ Wf2, const float* __restrict__ b1,
           const float* __restrict__ b2, ushort* __restrict__ Hout,
           const int* __restrict__ batch, float* __restrict__ pool,
           int col_off, int M) {
  __shared__ uint lt[4][1024];
  const int lane = threadIdx.x & 63;
  const int wid = threadIdx.x >> 6;
  uint* T = lt[wid];
  const int m0 = blockIdx.x * 64 + wid * 16;
  if (m0 >= M) return;
  const int row = lane & 15, hi = lane >> 4;

  // GEMM1: A-frags direct from global z (coalesced 16B/lane)
  f32x4 acc[8];
#pragma unroll
  for (int nt = 0; nt < 8; ++nt) acc[nt] = (f32x4){0.f, 0.f, 0.f, 0.f};
  {
    const s16x8* zrow = (const s16x8*)(Z + (size_t)(m0 + row) * 128);
    const s16x8* wf = (const s16x8*)Wf1;
#pragma unroll
    for (int ks = 0; ks < 4; ++ks) {
      s16x8 af = zrow[ks * 4 + hi];
#pragma unroll
      for (int nt = 0; nt < 8; ++nt)
        acc[nt] = __builtin_amdgcn_mfma_f32_16x16x32_bf16(af, wf[(nt * 4 + ks) * 64 + lane], acc[nt], 0, 0, 0);
    }
  }
  // epilogue1: bias + relu -> swizzled LDS t-tile (wave-private, no barrier)
  {
    ushort* Tb = (ushort*)T;
    const int r0l = hi * 4;
#pragma unroll
    for (int nt = 0; nt < 8; ++nt) {
      float bb = b1[nt * 16 + row];
      const int col = nt * 16 + row;
#pragma unroll
      for (int i = 0; i < 4; ++i) {
        int lr = r0l + i;
        float v = fmaxf(acc[nt][i] + bb, 0.f);
        Tb[(lr * 128 + col) ^ ((lr & 7) << 3)] = f2bf(v);
      }
    }
  }
  // GEMM2 from LDS + epilogue2: write h' + pool
#pragma unroll
  for (int nt = 0; nt < 8; ++nt) acc[nt] = (f32x4){0.f, 0.f, 0.f, 0.f};
  gemm_lds(T, (const s16x8*)Wf2, acc, lane);
  {
    const int r0 = m0 + hi * 4;
    const int gf = batch[m0];
    const int gl = batch[m0 + 15];
#pragma unroll
    for (int nt = 0; nt < 8; ++nt) {
      const int col = nt * 16 + row;
      float bb = b2[col];
      float vs = 0.f;
#pragma unroll
      for (int i = 0; i < 4; ++i) {
        float v = acc[nt][i] + bb;
        Hout[(size_t)(r0 + i) * 128 + col] = f2bf(v);
        vs += v;
      }
      if (gf == gl) {
        vs += __shfl_xor(vs, 16);
        vs += __shfl_xor(vs, 32);
        if (lane < 16) atomicAdd(&pool[(size_t)gf * 384 + col_off + nt * 16 + lane], vs);
      } else {
#pragma unroll
        for (int i = 0; i < 4; ++i) {
          float v = acc[nt][i] + bb;
          int g = batch[r0 + i];
          atomicAdd(&pool[(size_t)g * 384 + col_off + col], v);
        }
      }
    }
  }
}

// ---------------- fused pre-MLP: h = relu(relu(x@Wp1+bp1)@Wp2+bp2), x f32 ----------------
__global__ __launch_bounds__(256, 4)
void k_mlp2(const float* __restrict__ X, const ushort* __restrict__ Wf1,
            const ushort* __restrict__ Wf2, const float* __restrict__ b1,
            const float* __restrict__ b2, ushort* __restrict__ Hout, int M) {
  __shared__ uint lt[4][1024];
  const int lane = threadIdx.x & 63;
  const int wid = threadIdx.x >> 6;
  uint* T = lt[wid];
  const int m0 = blockIdx.x * 64 + wid * 16;
  if (m0 >= M) return;
  const int row = lane & 15, hi = lane >> 4;

  f32x4 acc[8];
#pragma unroll
  for (int nt = 0; nt < 8; ++nt) acc[nt] = (f32x4){0.f, 0.f, 0.f, 0.f};
  {
    const float* xrow = X + (size_t)(m0 + row) * 128;
    const s16x8* wf = (const s16x8*)Wf1;
#pragma unroll
    for (int ks = 0; ks < 4; ++ks) {
      float4 xa = *(const float4*)&xrow[ks * 32 + hi * 8];
      float4 xb = *(const float4*)&xrow[ks * 32 + hi * 8 + 4];
      s16x8 af;
      af[0] = (short)f2bf(xa.x); af[1] = (short)f2bf(xa.y);
      af[2] = (short)f2bf(xa.z); af[3] = (short)f2bf(xa.w);
      af[4] = (short)f2bf(xb.x); af[5] = (short)f2bf(xb.y);
      af[6] = (short)f2bf(xb.z); af[7] = (short)f2bf(xb.w);
#pragma unroll
      for (int nt = 0; nt < 8; ++nt)
        acc[nt] = __builtin_amdgcn_mfma_f32_16x16x32_bf16(af, wf[(nt * 4 + ks) * 64 + lane], acc[nt], 0, 0, 0);
    }
  }
  {
    ushort* Tb = (ushort*)T;
    const int r0l = hi * 4;
#pragma unroll
    for (int nt = 0; nt < 8; ++nt) {
      float bb = b1[nt * 16 + row];
      const int col = nt * 16 + row;
#pragma unroll
      for (int i = 0; i < 4; ++i) {
        int lr = r0l + i;
        float v = fmaxf(acc[nt][i] + bb, 0.f);
        Tb[(lr * 128 + col) ^ ((lr & 7) << 3)] = f2bf(v);
      }
    }
  }
#pragma unroll
  for (int nt = 0; nt < 8; ++nt) acc[nt] = (f32x4){0.f, 0.f, 0.f, 0.f};
  gemm_lds(T, (const s16x8*)Wf2, acc, lane);
  {
    const int r0 = m0 + hi * 4;
#pragma unroll
    for (int nt = 0; nt < 8; ++nt) {
      const int col = nt * 16 + row;
      float bb = b2[col];
#pragma unroll
      for (int i = 0; i < 4; ++i) {
        float v = fmaxf(acc[nt][i] + bb, 0.f);
        Hout[(size_t)(r0 + i) * 128 + col] = f2bf(v);
      }
    }
  }
}

extern "C" void kernel_launch(void* const* d_in, const int* in_sizes, int n_in,
                              void* d_out, int out_size, void* d_ws, size_t ws_size,
                              hipStream_t stream) {
  const float* x    = (const float*)d_in[0];
  const int*   ei   = (const int*)d_in[1];
  const int*   batch= (const int*)d_in[2];
  const float* Wp1  = (const float*)d_in[3];
  const float* bp1  = (const float*)d_in[4];
  const float* Wp2  = (const float*)d_in[5];
  const float* bp2  = (const float*)d_in[6];
  const float* W1s  = (const float*)d_in[7];
  const float* b1s  = (const float*)d_in[8];
  const float* W2s  = (const float*)d_in[9];
  const float* b2s  = (const float*)d_in[10];
  const float* eps  = (const float*)d_in[11];

  const int N = in_sizes[0] / 128;
  const int E = in_sizes[1] / 2;
  float* out = (float*)d_out;
  const int nbk = (N + 2047) >> 11;

  char* ws = (char*)d_ws;
  size_t off = 0;
  auto alloc = [&](size_t bytes) -> void* {
    void* p = ws + off;
    off += (bytes + 255) & ~(size_t)255;
    return p;
  };
  ushort* bufA  = (ushort*)alloc((size_t)N * 128 * 2);
  ushort* bufB  = (ushort*)alloc((size_t)N * 128 * 2);
  ushort* bufZ  = (ushort*)alloc((size_t)N * 128 * 2);
  ushort* Wf    = (ushort*)alloc((size_t)8 * 16384 * 2);
  int* rowbeg   = (int*)alloc((size_t)N * 4);
  int* rowend   = (int*)alloc((size_t)N * 4);
  int* csr      = (int*)alloc((size_t)nbk * ECAP * 4);
  uint2* ebuf   = (uint2*)alloc((size_t)nbk * ECAP * 8);
  int* bcur     = (int*)alloc((size_t)(nbk + 1) * 4);
  (void)ws_size; (void)n_in;

  hipMemsetAsync(out, 0, (size_t)out_size * 4, stream);

  k_prepw<<<64, 256, 0, stream>>>(Wp1, Wp2, W1s, W2s, Wf);
  k_binit<<<1, 64, 0, stream>>>(bcur, nbk);
  k_part<<<(E + PEPB - 1) / PEPB, 256, 0, stream>>>(ei, ei + E, bcur, ebuf, E);
  k_sort<<<nbk, 1024, 0, stream>>>(ebuf, bcur, rowbeg, rowend, csr, N);

  const int ngrid = (N + 63) / 64;
  k_mlp2<<<ngrid, 256, 0, stream>>>(x, Wf + 0 * 16384, Wf + 1 * 16384, bp1, bp2, bufA, N);

  // chunked agg grid: 4 chunks x ceil(N/16) node-blocks, packed 8 blocks/XCD-round
  const int nbpc = (N + 15) / 16;
  const int agrid = ((nbpc + 1) >> 1) * 8;

  ushort* hin = bufA;
  ushort* hout = bufB;
  for (int L = 0; L < 3; ++L) {
    k_agg<<<agrid, 256, 0, stream>>>(hin, rowbeg, rowend, csr, bufZ, eps, L, N);
    k_mlp<<<ngrid, 256, 0, stream>>>(bufZ, Wf + (2 + L) * 16384, Wf + (5 + L) * 16384,
                                     b1s + (size_t)L * 128, b2s + (size_t)L * 128,
                                     hout, batch, out, L * 128, N);
    ushort* tmp = hin; hin = hout; hout = tmp;
  }
}

// Round 8
// 369.149 us; speedup vs baseline: 1.4271x; 1.4271x over previous
//
#include <hip/hip_runtime.h>

typedef float f32x4 __attribute__((ext_vector_type(4)));
typedef short s16x8 __attribute__((ext_vector_type(8)));

#define ECAP 36864   // padded per-bucket edge capacity (mean 32768, +22 sigma)

__device__ __forceinline__ ushort f2bf(float f) {
  uint u = __builtin_bit_cast(uint, f);
  u += 0x7fffu + ((u >> 16) & 1u);
  return (ushort)(u >> 16);
}
__device__ __forceinline__ float bfu_lo(uint u) { return __builtin_bit_cast(float, u << 16); }
__device__ __forceinline__ float bfu_hi(uint u) { return __builtin_bit_cast(float, u & 0xffff0000u); }

// ---------------- reformat 8 weight matrices into MFMA B-fragment order ----------------
// Wf[m][(nt*4+ks)*64 + lane][i] = bf16( W_m[ks*32 + (lane>>4)*8 + i][nt*16 + (lane&15)] )
// also initializes bcur (bucket cursors) to fold out the k_binit launch
__global__ void k_prepw(const float* __restrict__ Wp1, const float* __restrict__ Wp2,
                        const float* __restrict__ W1s, const float* __restrict__ W2s,
                        ushort* __restrict__ Wf, int* __restrict__ bcur, int nbk) {
  int t = blockIdx.x * blockDim.x + threadIdx.x;
  if (t <= nbk) bcur[t] = t * ECAP;
  if (t >= 8 * 2048) return;
  int m = t >> 11;
  int r = t & 2047;
  int lane = r & 63;
  int ksnt = r >> 6;
  int ks = ksnt & 3;
  int nt = ksnt >> 2;
  const float* src = (m == 0) ? Wp1 : (m == 1) ? Wp2
                     : (m < 5) ? (W1s + (size_t)(m - 2) * 16384)
                               : (W2s + (size_t)(m - 5) * 16384);
  ushort* dst = Wf + (size_t)m * 16384 + (size_t)r * 8;
  int c = nt * 16 + (lane & 15);
  int kbase = ks * 32 + (lane >> 4) * 8;
  for (int i = 0; i < 8; ++i) dst[i] = f2bf(src[(size_t)(kbase + i) * 128 + c]);
}

// ---------------- LDS-staged multi-split: partition edges into dst-range buckets ---------
#define PNBK 64
#define PCAP 80
#define PEPB 2048
__global__ __launch_bounds__(256)
void k_part(const int* __restrict__ src, const int* __restrict__ dst,
            int* __restrict__ bcur, uint2* __restrict__ ebuf, int E) {
  __shared__ uint2 stage[PNBK][PCAP];
  __shared__ int lcnt[PNBK];
  int tid = threadIdx.x;
  if (tid < PNBK) lcnt[tid] = 0;
  __syncthreads();
  int e0 = blockIdx.x * PEPB;
  for (int r = 0; r < PEPB / 256; ++r) {
    int e = e0 + r * 256 + tid;
    if (e < E) {
      int d = dst[e], s = src[e];
      int b = d >> 11;
      int pos = atomicAdd(&lcnt[b], 1);
      uint2 pr; pr.x = (uint)s; pr.y = (uint)d;
      if (pos < PCAP) {
        stage[b][pos] = pr;
      } else {  // overflow fallback (correct for any data)
        int p = atomicAdd(&bcur[b], 1);
        ebuf[p] = pr;
      }
    }
    if (r == 3 || r == PEPB / 256 - 1) {
      __syncthreads();
      if (tid < PNBK) {
        int c = lcnt[tid];
        if (c > PCAP) c = PCAP;
        if (c > 0) {
          int base = atomicAdd(&bcur[tid], c);
          for (int i = 0; i < c; ++i) ebuf[base + i] = stage[tid][i];
          lcnt[tid] = 0;
        }
      }
      __syncthreads();
    }
  }
}

// ---------------- per-bucket LDS counting sort ----------------
__global__ __launch_bounds__(1024)
void k_sort(const uint2* __restrict__ ebuf, const int* __restrict__ bcur,
            int* __restrict__ rowbeg, int* __restrict__ rowend,
            int* __restrict__ csr, int N) {
  __shared__ int lcnt[2048];
  __shared__ int loff[2048];
  __shared__ int wsum[16];
  const int b = blockIdx.x;
  const int tid = threadIdx.x;
  const int lane = tid & 63, w = tid >> 6;
  const int base_e = b * ECAP;
  const int node0 = b << 11;
  const int ecnt = bcur[b] - base_e;

  lcnt[tid] = 0; lcnt[tid + 1024] = 0;
  __syncthreads();
  for (int i = tid; i < ecnt; i += 1024) {
    int d = (int)ebuf[base_e + i].y;
    atomicAdd(&lcnt[d - node0], 1);
  }
  __syncthreads();
  int v0 = lcnt[2 * tid], v1 = lcnt[2 * tid + 1];
  int s = v0 + v1;
  for (int off = 1; off < 64; off <<= 1) {
    int t = __shfl_up(s, off);
    if (lane >= off) s += t;
  }
  if (lane == 63) wsum[w] = s;
  __syncthreads();
  if (w == 0 && lane < 16) {
    int x = wsum[lane];
    int sx = x;
    for (int off = 1; off < 16; off <<= 1) {
      int t = __shfl_up(sx, off);
      if (lane >= off) sx += t;
    }
    wsum[lane] = sx - x;
  }
  __syncthreads();
  int excl = wsum[w] + (s - v0 - v1);
  loff[2 * tid] = excl;
  loff[2 * tid + 1] = excl + v0;
  __syncthreads();
  for (int i = tid; i < 2048; i += 1024) {
    int g = node0 + i;
    if (g < N) {
      int rb = base_e + loff[i];
      rowbeg[g] = rb;
      rowend[g] = rb + lcnt[i];
    }
    lcnt[i] = 0;
  }
  __syncthreads();
  for (int i = tid; i < ecnt; i += 1024) {
    uint2 p = ebuf[base_e + i];
    int dloc = (int)p.y - node0;
    int pos = base_e + loff[dloc] + atomicAdd(&lcnt[dloc], 1);
    csr[pos] = (int)p.x;
  }
}

// ---------------- fused GIN layer: 32-row tile, 8 waves ----------------
// gather: wave w owns rows w*4..w*4+3 (full-wave 256B row loads, proven R4 structure)
// MLP:    wave w = (rowsub = w>>2) x (col chunk c2 = (w&3)*2 nt-pairs)
__global__ __launch_bounds__(512, 8)
void k_layer(const ushort* __restrict__ H, const int* __restrict__ rowbeg,
             const int* __restrict__ rowend, const int* __restrict__ csr,
             const ushort* __restrict__ Wf1, const ushort* __restrict__ Wf2,
             const float* __restrict__ b1, const float* __restrict__ b2,
             const float* __restrict__ eps, int layer,
             ushort* __restrict__ Hout, const int* __restrict__ batch,
             float* __restrict__ pool, int col_off, int M) {
  __shared__ uint T[2048];   // 32 rows x 64 uints (bf16x2), XOR-swizzled
  const int tid = threadIdx.x;
  const int w = tid >> 6, lane = tid & 63;
  const int m0 = blockIdx.x * 32;
  const float e = 1.0f + eps[layer];
  const uint* h32 = (const uint*)H;

  // ---- phase A: gather z rows (4 per wave) ----
  for (int r = 0; r < 4; ++r) {
    const int row = w * 4 + r;
    const int n = m0 + row;
    if (n < M) {
      uint u = h32[(size_t)n * 64 + lane];
      float a0 = bfu_lo(u) * e, a1 = bfu_hi(u) * e;
      int s0 = rowbeg[n], s1 = rowend[n];
      for (int base = s0; base < s1; base += 64) {
        int cnt = s1 - base;
        if (cnt > 64) cnt = 64;
        int idx = (lane < cnt) ? csr[base + lane] : 0;
        int j = 0;
        for (; j + 4 <= cnt; j += 4) {
          int i0 = __shfl(idx, j), i1 = __shfl(idx, j + 1);
          int i2 = __shfl(idx, j + 2), i3 = __shfl(idx, j + 3);
          uint u0 = h32[(size_t)i0 * 64 + lane];
          uint u1 = h32[(size_t)i1 * 64 + lane];
          uint u2 = h32[(size_t)i2 * 64 + lane];
          uint u3 = h32[(size_t)i3 * 64 + lane];
          a0 += bfu_lo(u0); a1 += bfu_hi(u0);
          a0 += bfu_lo(u1); a1 += bfu_hi(u1);
          a0 += bfu_lo(u2); a1 += bfu_hi(u2);
          a0 += bfu_lo(u3); a1 += bfu_hi(u3);
        }
        for (; j < cnt; ++j) {
          int si = __shfl(idx, j);
          uint uu = h32[(size_t)si * 64 + lane];
          a0 += bfu_lo(uu); a1 += bfu_hi(uu);
        }
      }
      T[row * 64 + (lane ^ ((row & 7) << 2))] = (uint)f2bf(a0) | ((uint)f2bf(a1) << 16);
    }
  }
  __syncthreads();

  // ---- phase B: GEMM1 (acc in regs) ----
  const int row16 = lane & 15, hi = lane >> 4;
  const int rowsub = w >> 2, c2 = (w & 3) << 1;
  const s16x8* wf1 = (const s16x8*)Wf1;
  f32x4 acc0 = (f32x4){0.f, 0.f, 0.f, 0.f};
  f32x4 acc1 = (f32x4){0.f, 0.f, 0.f, 0.f};
#pragma unroll
  for (int ks = 0; ks < 4; ++ks) {
    const s16x8 af = *(const s16x8*)(T + (rowsub * 16 + row16) * 64 +
                                     ((ks * 16 + hi * 4) ^ ((row16 & 7) << 2)));
    acc0 = __builtin_amdgcn_mfma_f32_16x16x32_bf16(af, wf1[((c2 + 0) * 4 + ks) * 64 + lane], acc0, 0, 0, 0);
    acc1 = __builtin_amdgcn_mfma_f32_16x16x32_bf16(af, wf1[((c2 + 1) * 4 + ks) * 64 + lane], acc1, 0, 0, 0);
  }
  __syncthreads();

  // ---- t = relu(.+b1) -> LDS (overwrite tile) ----
  {
    ushort* Tb = (ushort*)T;
    const float bb0 = b1[(c2 + 0) * 16 + row16];
    const float bb1 = b1[(c2 + 1) * 16 + row16];
#pragma unroll
    for (int i = 0; i < 4; ++i) {
      const int rr = rowsub * 16 + hi * 4 + i;
      Tb[(rr * 128 + (c2 + 0) * 16 + row16) ^ ((rr & 7) << 3)] = f2bf(fmaxf(acc0[i] + bb0, 0.f));
      Tb[(rr * 128 + (c2 + 1) * 16 + row16) ^ ((rr & 7) << 3)] = f2bf(fmaxf(acc1[i] + bb1, 0.f));
    }
  }
  __syncthreads();

  // ---- phase C: GEMM2 + write + pool ----
  const s16x8* wf2 = (const s16x8*)Wf2;
  f32x4 ac0 = (f32x4){0.f, 0.f, 0.f, 0.f};
  f32x4 ac1 = (f32x4){0.f, 0.f, 0.f, 0.f};
#pragma unroll
  for (int ks = 0; ks < 4; ++ks) {
    const s16x8 af = *(const s16x8*)(T + (rowsub * 16 + row16) * 64 +
                                     ((ks * 16 + hi * 4) ^ ((row16 & 7) << 2)));
    ac0 = __builtin_amdgcn_mfma_f32_16x16x32_bf16(af, wf2[((c2 + 0) * 4 + ks) * 64 + lane], ac0, 0, 0, 0);
    ac1 = __builtin_amdgcn_mfma_f32_16x16x32_bf16(af, wf2[((c2 + 1) * 4 + ks) * 64 + lane], ac1, 0, 0, 0);
  }
  {
    const int rbase = m0 + rowsub * 16;
    const int r0 = rbase + hi * 4;
    const int col0 = (c2 + 0) * 16 + row16, col1 = (c2 + 1) * 16 + row16;
    const float bb0 = b2[col0], bb1 = b2[col1];
    const bool full = (rbase + 15 < M);
    const int gf = batch[rbase < M ? rbase : (M - 1)];
    const int gl = batch[(rbase + 15) < M ? (rbase + 15) : (M - 1)];
    if (full && gf == gl) {
      float vs0 = 0.f, vs1 = 0.f;
#pragma unroll
      for (int i = 0; i < 4; ++i) {
        float v0 = ac0[i] + bb0, v1 = ac1[i] + bb1;
        Hout[(size_t)(r0 + i) * 128 + col0] = f2bf(v0);
        Hout[(size_t)(r0 + i) * 128 + col1] = f2bf(v1);
        vs0 += v0; vs1 += v1;
      }
      vs0 += __shfl_xor(vs0, 16); vs0 += __shfl_xor(vs0, 32);
      vs1 += __shfl_xor(vs1, 16); vs1 += __shfl_xor(vs1, 32);
      if (lane < 16) {
        atomicAdd(&pool[(size_t)gf * 384 + col_off + (c2 + 0) * 16 + lane], vs0);
        atomicAdd(&pool[(size_t)gf * 384 + col_off + (c2 + 1) * 16 + lane], vs1);
      }
    } else {
#pragma unroll
      for (int i = 0; i < 4; ++i) {
        const int rr = r0 + i;
        if (rr < M) {
          float v0 = ac0[i] + bb0, v1 = ac1[i] + bb1;
          Hout[(size_t)rr * 128 + col0] = f2bf(v0);
          Hout[(size_t)rr * 128 + col1] = f2bf(v1);
          int g = batch[rr];
          atomicAdd(&pool[(size_t)g * 384 + col_off + col0], v0);
          atomicAdd(&pool[(size_t)g * 384 + col_off + col1], v1);
        }
      }
    }
  }
}

// ---------------- fused pre-MLP: h = relu(relu(x@Wp1+bp1)@Wp2+bp2), x f32 ----------------
__global__ __launch_bounds__(256, 4)
void k_mlp2(const float* __restrict__ X, const ushort* __restrict__ Wf1,
            const ushort* __restrict__ Wf2, const float* __restrict__ b1,
            const float* __restrict__ b2, ushort* __restrict__ Hout, int M) {
  __shared__ uint lt[4][1024];
  const int lane = threadIdx.x & 63;
  const int wid = threadIdx.x >> 6;
  uint* T = lt[wid];
  const int m0 = blockIdx.x * 64 + wid * 16;
  if (m0 >= M) return;
  const int row = lane & 15, hi = lane >> 4;

  f32x4 acc[8];
#pragma unroll
  for (int nt = 0; nt < 8; ++nt) acc[nt] = (f32x4){0.f, 0.f, 0.f, 0.f};
  {
    const float* xrow = X + (size_t)(m0 + row) * 128;
    const s16x8* wf = (const s16x8*)Wf1;
#pragma unroll
    for (int ks = 0; ks < 4; ++ks) {
      float4 xa = *(const float4*)&xrow[ks * 32 + hi * 8];
      float4 xb = *(const float4*)&xrow[ks * 32 + hi * 8 + 4];
      s16x8 af;
      af[0] = (short)f2bf(xa.x); af[1] = (short)f2bf(xa.y);
      af[2] = (short)f2bf(xa.z); af[3] = (short)f2bf(xa.w);
      af[4] = (short)f2bf(xb.x); af[5] = (short)f2bf(xb.y);
      af[6] = (short)f2bf(xb.z); af[7] = (short)f2bf(xb.w);
#pragma unroll
      for (int nt = 0; nt < 8; ++nt)
        acc[nt] = __builtin_amdgcn_mfma_f32_16x16x32_bf16(af, wf[(nt * 4 + ks) * 64 + lane], acc[nt], 0, 0, 0);
    }
  }
  {
    ushort* Tb = (ushort*)T;
    const int r0l = hi * 4;
#pragma unroll
    for (int nt = 0; nt < 8; ++nt) {
      float bb = b1[nt * 16 + row];
      const int col = nt * 16 + row;
#pragma unroll
      for (int i = 0; i < 4; ++i) {
        int lr = r0l + i;
        float v = fmaxf(acc[nt][i] + bb, 0.f);
        Tb[(lr * 128 + col) ^ ((lr & 7) << 3)] = f2bf(v);
      }
    }
  }
#pragma unroll
  for (int nt = 0; nt < 8; ++nt) acc[nt] = (f32x4){0.f, 0.f, 0.f, 0.f};
  {
#pragma unroll
    for (int ks = 0; ks < 4; ++ks) {
      int ub = row * 64 + ((ks * 16 + hi * 4) ^ ((row & 7) << 2));
      s16x8 af = *(const s16x8*)(T + ub);
#pragma unroll
      for (int nt = 0; nt < 8; ++nt)
        acc[nt] = __builtin_amdgcn_mfma_f32_16x16x32_bf16(af, ((const s16x8*)Wf2)[(nt * 4 + ks) * 64 + lane], acc[nt], 0, 0, 0);
    }
  }
  {
    const int r0 = m0 + hi * 4;
#pragma unroll
    for (int nt = 0; nt < 8; ++nt) {
      const int col = nt * 16 + row;
      float bb = b2[col];
#pragma unroll
      for (int i = 0; i < 4; ++i) {
        float v = fmaxf(acc[nt][i] + bb, 0.f);
        Hout[(size_t)(r0 + i) * 128 + col] = f2bf(v);
      }
    }
  }
}

extern "C" void kernel_launch(void* const* d_in, const int* in_sizes, int n_in,
                              void* d_out, int out_size, void* d_ws, size_t ws_size,
                              hipStream_t stream) {
  const float* x    = (const float*)d_in[0];
  const int*   ei   = (const int*)d_in[1];
  const int*   batch= (const int*)d_in[2];
  const float* Wp1  = (const float*)d_in[3];
  const float* bp1  = (const float*)d_in[4];
  const float* Wp2  = (const float*)d_in[5];
  const float* bp2  = (const float*)d_in[6];
  const float* W1s  = (const float*)d_in[7];
  const float* b1s  = (const float*)d_in[8];
  const float* W2s  = (const float*)d_in[9];
  const float* b2s  = (const float*)d_in[10];
  const float* eps  = (const float*)d_in[11];

  const int N = in_sizes[0] / 128;
  const int E = in_sizes[1] / 2;
  float* out = (float*)d_out;
  const int nbk = (N + 2047) >> 11;

  char* ws = (char*)d_ws;
  size_t off = 0;
  auto alloc = [&](size_t bytes) -> void* {
    void* p = ws + off;
    off += (bytes + 255) & ~(size_t)255;
    return p;
  };
  ushort* bufA  = (ushort*)alloc((size_t)N * 128 * 2);
  ushort* bufB  = (ushort*)alloc((size_t)N * 128 * 2);
  ushort* Wf    = (ushort*)alloc((size_t)8 * 16384 * 2);
  int* rowbeg   = (int*)alloc((size_t)N * 4);
  int* rowend   = (int*)alloc((size_t)N * 4);
  int* csr      = (int*)alloc((size_t)nbk * ECAP * 4);
  uint2* ebuf   = (uint2*)alloc((size_t)nbk * ECAP * 8);
  int* bcur     = (int*)alloc((size_t)(nbk + 1) * 4);
  (void)ws_size; (void)n_in;

  hipMemsetAsync(out, 0, (size_t)out_size * 4, stream);

  k_prepw<<<64, 256, 0, stream>>>(Wp1, Wp2, W1s, W2s, Wf, bcur, nbk);
  k_part<<<(E + PEPB - 1) / PEPB, 256, 0, stream>>>(ei, ei + E, bcur, ebuf, E);
  k_sort<<<nbk, 1024, 0, stream>>>(ebuf, bcur, rowbeg, rowend, csr, N);

  const int ngrid = (N + 63) / 64;
  k_mlp2<<<ngrid, 256, 0, stream>>>(x, Wf + 0 * 16384, Wf + 1 * 16384, bp1, bp2, bufA, N);

  const int lgrid = (N + 31) / 32;
  ushort* hin = bufA;
  ushort* hout = bufB;
  for (int L = 0; L < 3; ++L) {
    k_layer<<<lgrid, 512, 0, stream>>>(hin, rowbeg, rowend, csr,
                                       Wf + (2 + L) * 16384, Wf + (5 + L) * 16384,
                                       b1s + (size_t)L * 128, b2s + (size_t)L * 128,
                                       eps, L, hout, batch, out, L * 128, N);
    ushort* tmp = hin; hin = hout; hout = tmp;
  }
}

// Round 9
// 362.459 us; speedup vs baseline: 1.4535x; 1.0185x over previous
//
#include <hip/hip_runtime.h>

typedef float f32x4 __attribute__((ext_vector_type(4)));
typedef short s16x8 __attribute__((ext_vector_type(8)));

#define ECAP 36864   // padded per-bucket edge capacity (mean 32768, +22 sigma)

__device__ __forceinline__ ushort f2bf(float f) {
  uint u = __builtin_bit_cast(uint, f);
  u += 0x7fffu + ((u >> 16) & 1u);
  return (ushort)(u >> 16);
}
__device__ __forceinline__ float bfu_lo(uint u) { return __builtin_bit_cast(float, u << 16); }
__device__ __forceinline__ float bfu_hi(uint u) { return __builtin_bit_cast(float, u & 0xffff0000u); }

// ---------------- reformat 8 weight matrices into MFMA B-fragment order ----------------
// Wf[m][(nt*4+ks)*64 + lane][i] = bf16( W_m[ks*32 + (lane>>4)*8 + i][nt*16 + (lane&15)] )
// also initializes bcur (bucket cursors)
__global__ void k_prepw(const float* __restrict__ Wp1, const float* __restrict__ Wp2,
                        const float* __restrict__ W1s, const float* __restrict__ W2s,
                        ushort* __restrict__ Wf, int* __restrict__ bcur, int nbk) {
  int t = blockIdx.x * blockDim.x + threadIdx.x;
  if (t <= nbk) bcur[t] = t * ECAP;
  if (t >= 8 * 2048) return;
  int m = t >> 11;
  int r = t & 2047;
  int lane = r & 63;
  int ksnt = r >> 6;
  int ks = ksnt & 3;
  int nt = ksnt >> 2;
  const float* src = (m == 0) ? Wp1 : (m == 1) ? Wp2
                     : (m < 5) ? (W1s + (size_t)(m - 2) * 16384)
                               : (W2s + (size_t)(m - 5) * 16384);
  ushort* dst = Wf + (size_t)m * 16384 + (size_t)r * 8;
  int c = nt * 16 + (lane & 15);
  int kbase = ks * 32 + (lane >> 4) * 8;
  for (int i = 0; i < 8; ++i) dst[i] = f2bf(src[(size_t)(kbase + i) * 128 + c]);
}

// ---------------- LDS-staged multi-split: partition edges into dst-range buckets ---------
#define PNBK 64
#define PCAP 80
#define PEPB 2048
__global__ __launch_bounds__(256)
void k_part(const int* __restrict__ src, const int* __restrict__ dst,
            int* __restrict__ bcur, uint2* __restrict__ ebuf, int E) {
  __shared__ uint2 stage[PNBK][PCAP];
  __shared__ int lcnt[PNBK];
  int tid = threadIdx.x;
  if (tid < PNBK) lcnt[tid] = 0;
  __syncthreads();
  int e0 = blockIdx.x * PEPB;
  for (int r = 0; r < PEPB / 256; ++r) {
    int e = e0 + r * 256 + tid;
    if (e < E) {
      int d = dst[e], s = src[e];
      int b = d >> 11;
      int pos = atomicAdd(&lcnt[b], 1);
      uint2 pr; pr.x = (uint)s; pr.y = (uint)d;
      if (pos < PCAP) {
        stage[b][pos] = pr;
      } else {  // overflow fallback (correct for any data)
        int p = atomicAdd(&bcur[b], 1);
        ebuf[p] = pr;
      }
    }
    if (r == 3 || r == PEPB / 256 - 1) {
      __syncthreads();
      if (tid < PNBK) {
        int c = lcnt[tid];
        if (c > PCAP) c = PCAP;
        if (c > 0) {
          int base = atomicAdd(&bcur[tid], c);
          for (int i = 0; i < c; ++i) ebuf[base + i] = stage[tid][i];
          lcnt[tid] = 0;
        }
      }
      __syncthreads();
    }
  }
}

// ---------------- per-bucket LDS counting sort ----------------
__global__ __launch_bounds__(1024)
void k_sort(const uint2* __restrict__ ebuf, const int* __restrict__ bcur,
            int* __restrict__ rowbeg, int* __restrict__ rowend,
            int* __restrict__ csr, int N) {
  __shared__ int lcnt[2048];
  __shared__ int loff[2048];
  __shared__ int wsum[16];
  const int b = blockIdx.x;
  const int tid = threadIdx.x;
  const int lane = tid & 63, w = tid >> 6;
  const int base_e = b * ECAP;
  const int node0 = b << 11;
  const int ecnt = bcur[b] - base_e;

  lcnt[tid] = 0; lcnt[tid + 1024] = 0;
  __syncthreads();
  for (int i = tid; i < ecnt; i += 1024) {
    int d = (int)ebuf[base_e + i].y;
    atomicAdd(&lcnt[d - node0], 1);
  }
  __syncthreads();
  int v0 = lcnt[2 * tid], v1 = lcnt[2 * tid + 1];
  int s = v0 + v1;
  for (int off = 1; off < 64; off <<= 1) {
    int t = __shfl_up(s, off);
    if (lane >= off) s += t;
  }
  if (lane == 63) wsum[w] = s;
  __syncthreads();
  if (w == 0 && lane < 16) {
    int x = wsum[lane];
    int sx = x;
    for (int off = 1; off < 16; off <<= 1) {
      int t = __shfl_up(sx, off);
      if (lane >= off) sx += t;
    }
    wsum[lane] = sx - x;
  }
  __syncthreads();
  int excl = wsum[w] + (s - v0 - v1);
  loff[2 * tid] = excl;
  loff[2 * tid + 1] = excl + v0;
  __syncthreads();
  for (int i = tid; i < 2048; i += 1024) {
    int g = node0 + i;
    if (g < N) {
      int rb = base_e + loff[i];
      rowbeg[g] = rb;
      rowend[g] = rb + lcnt[i];
    }
    lcnt[i] = 0;
  }
  __syncthreads();
  for (int i = tid; i < ecnt; i += 1024) {
    uint2 p = ebuf[base_e + i];
    int dloc = (int)p.y - node0;
    int pos = base_e + loff[dloc] + atomicAdd(&lcnt[dloc], 1);
    csr[pos] = (int)p.x;
  }
}

// ---------------- fused GIN layer: 16-row tile, 4 waves, 8 blocks/CU ----------------
// gather: wave w owns rows w*4..w*4+3 (full-wave 256B row loads, R4 structure)
// MLP:    wave w computes nt chunks {2w, 2w+1} for all 16 rows
// two LDS tiles (z in Tz, t in Tt) -> only 2 barriers
__global__ __launch_bounds__(256, 8)
void k_layer(const ushort* __restrict__ H, const int* __restrict__ rowbeg,
             const int* __restrict__ rowend, const int* __restrict__ csr,
             const ushort* __restrict__ Wf1, const ushort* __restrict__ Wf2,
             const float* __restrict__ b1, const float* __restrict__ b2,
             const float* __restrict__ eps, int layer,
             ushort* __restrict__ Hout, const int* __restrict__ batch,
             float* __restrict__ pool, int col_off, int M) {
  __shared__ uint Tz[1024];   // 16 rows x 64 uints (bf16x2), XOR-swizzled
  __shared__ uint Tt[1024];
  const int tid = threadIdx.x;
  const int w = tid >> 6, lane = tid & 63;
  const int m0 = blockIdx.x * 16;
  const float e = 1.0f + eps[layer];
  const uint* h32 = (const uint*)H;

  // ---- phase A: gather z rows (4 per wave) ----
  for (int r = 0; r < 4; ++r) {
    const int row = w * 4 + r;
    const int n = m0 + row;
    if (n < M) {
      uint u = h32[(size_t)n * 64 + lane];
      float a0 = bfu_lo(u) * e, a1 = bfu_hi(u) * e;
      int s0 = rowbeg[n], s1 = rowend[n];
      for (int base = s0; base < s1; base += 64) {
        int cnt = s1 - base;
        if (cnt > 64) cnt = 64;
        int idx = (lane < cnt) ? csr[base + lane] : 0;
        int j = 0;
        for (; j + 4 <= cnt; j += 4) {
          int i0 = __shfl(idx, j), i1 = __shfl(idx, j + 1);
          int i2 = __shfl(idx, j + 2), i3 = __shfl(idx, j + 3);
          uint u0 = h32[(size_t)i0 * 64 + lane];
          uint u1 = h32[(size_t)i1 * 64 + lane];
          uint u2 = h32[(size_t)i2 * 64 + lane];
          uint u3 = h32[(size_t)i3 * 64 + lane];
          a0 += bfu_lo(u0); a1 += bfu_hi(u0);
          a0 += bfu_lo(u1); a1 += bfu_hi(u1);
          a0 += bfu_lo(u2); a1 += bfu_hi(u2);
          a0 += bfu_lo(u3); a1 += bfu_hi(u3);
        }
        for (; j < cnt; ++j) {
          int si = __shfl(idx, j);
          uint uu = h32[(size_t)si * 64 + lane];
          a0 += bfu_lo(uu); a1 += bfu_hi(uu);
        }
      }
      Tz[row * 64 + (lane ^ ((row & 7) << 2))] = (uint)f2bf(a0) | ((uint)f2bf(a1) << 16);
    }
  }
  __syncthreads();

  // ---- phase B: GEMM1 (read Tz) -> relu -> Tt (no barrier between: different tiles) ----
  const int row16 = lane & 15, hi = lane >> 4;
  const int c2 = w << 1;
  const s16x8* wf1 = (const s16x8*)Wf1;
  f32x4 acc0 = (f32x4){0.f, 0.f, 0.f, 0.f};
  f32x4 acc1 = (f32x4){0.f, 0.f, 0.f, 0.f};
#pragma unroll
  for (int ks = 0; ks < 4; ++ks) {
    const s16x8 af = *(const s16x8*)(Tz + row16 * 64 + ((ks * 16 + hi * 4) ^ ((row16 & 7) << 2)));
    acc0 = __builtin_amdgcn_mfma_f32_16x16x32_bf16(af, wf1[((c2 + 0) * 4 + ks) * 64 + lane], acc0, 0, 0, 0);
    acc1 = __builtin_amdgcn_mfma_f32_16x16x32_bf16(af, wf1[((c2 + 1) * 4 + ks) * 64 + lane], acc1, 0, 0, 0);
  }
  {
    ushort* Tb = (ushort*)Tt;
    const float bb0 = b1[(c2 + 0) * 16 + row16];
    const float bb1 = b1[(c2 + 1) * 16 + row16];
#pragma unroll
    for (int i = 0; i < 4; ++i) {
      const int rr = hi * 4 + i;
      Tb[(rr * 128 + (c2 + 0) * 16 + row16) ^ ((rr & 7) << 3)] = f2bf(fmaxf(acc0[i] + bb0, 0.f));
      Tb[(rr * 128 + (c2 + 1) * 16 + row16) ^ ((rr & 7) << 3)] = f2bf(fmaxf(acc1[i] + bb1, 0.f));
    }
  }
  __syncthreads();

  // ---- phase C: GEMM2 (read Tt) + write + pool ----
  const s16x8* wf2 = (const s16x8*)Wf2;
  f32x4 ac0 = (f32x4){0.f, 0.f, 0.f, 0.f};
  f32x4 ac1 = (f32x4){0.f, 0.f, 0.f, 0.f};
#pragma unroll
  for (int ks = 0; ks < 4; ++ks) {
    const s16x8 af = *(const s16x8*)(Tt + row16 * 64 + ((ks * 16 + hi * 4) ^ ((row16 & 7) << 2)));
    ac0 = __builtin_amdgcn_mfma_f32_16x16x32_bf16(af, wf2[((c2 + 0) * 4 + ks) * 64 + lane], ac0, 0, 0, 0);
    ac1 = __builtin_amdgcn_mfma_f32_16x16x32_bf16(af, wf2[((c2 + 1) * 4 + ks) * 64 + lane], ac1, 0, 0, 0);
  }
  {
    const int r0 = m0 + hi * 4;
    const int col0 = (c2 + 0) * 16 + row16, col1 = (c2 + 1) * 16 + row16;
    const float bb0 = b2[col0], bb1 = b2[col1];
    const bool full = (m0 + 15 < M);
    const int gf = batch[m0 < M ? m0 : (M - 1)];
    const int gl = batch[(m0 + 15) < M ? (m0 + 15) : (M - 1)];
    if (full && gf == gl) {
      float vs0 = 0.f, vs1 = 0.f;
#pragma unroll
      for (int i = 0; i < 4; ++i) {
        float v0 = ac0[i] + bb0, v1 = ac1[i] + bb1;
        Hout[(size_t)(r0 + i) * 128 + col0] = f2bf(v0);
        Hout[(size_t)(r0 + i) * 128 + col1] = f2bf(v1);
        vs0 += v0; vs1 += v1;
      }
      vs0 += __shfl_xor(vs0, 16); vs0 += __shfl_xor(vs0, 32);
      vs1 += __shfl_xor(vs1, 16); vs1 += __shfl_xor(vs1, 32);
      if (lane < 16) {
        atomicAdd(&pool[(size_t)gf * 384 + col_off + (c2 + 0) * 16 + lane], vs0);
        atomicAdd(&pool[(size_t)gf * 384 + col_off + (c2 + 1) * 16 + lane], vs1);
      }
    } else {
#pragma unroll
      for (int i = 0; i < 4; ++i) {
        const int rr = r0 + i;
        if (rr < M) {
          float v0 = ac0[i] + bb0, v1 = ac1[i] + bb1;
          Hout[(size_t)rr * 128 + col0] = f2bf(v0);
          Hout[(size_t)rr * 128 + col1] = f2bf(v1);
          int g = batch[rr];
          atomicAdd(&pool[(size_t)g * 384 + col_off + col0], v0);
          atomicAdd(&pool[(size_t)g * 384 + col_off + col1], v1);
        }
      }
    }
  }
}

// ---------------- fused pre-MLP: h = relu(relu(x@Wp1+bp1)@Wp2+bp2), x f32 ----------------
__global__ __launch_bounds__(256, 4)
void k_mlp2(const float* __restrict__ X, const ushort* __restrict__ Wf1,
            const ushort* __restrict__ Wf2, const float* __restrict__ b1,
            const float* __restrict__ b2, ushort* __restrict__ Hout, int M) {
  __shared__ uint lt[4][1024];
  const int lane = threadIdx.x & 63;
  const int wid = threadIdx.x >> 6;
  uint* T = lt[wid];
  const int m0 = blockIdx.x * 64 + wid * 16;
  if (m0 >= M) return;
  const int row = lane & 15, hi = lane >> 4;

  f32x4 acc[8];
#pragma unroll
  for (int nt = 0; nt < 8; ++nt) acc[nt] = (f32x4){0.f, 0.f, 0.f, 0.f};
  {
    const float* xrow = X + (size_t)(m0 + row) * 128;
    const s16x8* wf = (const s16x8*)Wf1;
#pragma unroll
    for (int ks = 0; ks < 4; ++ks) {
      float4 xa = *(const float4*)&xrow[ks * 32 + hi * 8];
      float4 xb = *(const float4*)&xrow[ks * 32 + hi * 8 + 4];
      s16x8 af;
      af[0] = (short)f2bf(xa.x); af[1] = (short)f2bf(xa.y);
      af[2] = (short)f2bf(xa.z); af[3] = (short)f2bf(xa.w);
      af[4] = (short)f2bf(xb.x); af[5] = (short)f2bf(xb.y);
      af[6] = (short)f2bf(xb.z); af[7] = (short)f2bf(xb.w);
#pragma unroll
      for (int nt = 0; nt < 8; ++nt)
        acc[nt] = __builtin_amdgcn_mfma_f32_16x16x32_bf16(af, wf[(nt * 4 + ks) * 64 + lane], acc[nt], 0, 0, 0);
    }
  }
  {
    ushort* Tb = (ushort*)T;
    const int r0l = hi * 4;
#pragma unroll
    for (int nt = 0; nt < 8; ++nt) {
      float bb = b1[nt * 16 + row];
      const int col = nt * 16 + row;
#pragma unroll
      for (int i = 0; i < 4; ++i) {
        int lr = r0l + i;
        float v = fmaxf(acc[nt][i] + bb, 0.f);
        Tb[(lr * 128 + col) ^ ((lr & 7) << 3)] = f2bf(v);
      }
    }
  }
#pragma unroll
  for (int nt = 0; nt < 8; ++nt) acc[nt] = (f32x4){0.f, 0.f, 0.f, 0.f};
  {
#pragma unroll
    for (int ks = 0; ks < 4; ++ks) {
      int ub = row * 64 + ((ks * 16 + hi * 4) ^ ((row & 7) << 2));
      s16x8 af = *(const s16x8*)(T + ub);
#pragma unroll
      for (int nt = 0; nt < 8; ++nt)
        acc[nt] = __builtin_amdgcn_mfma_f32_16x16x32_bf16(af, ((const s16x8*)Wf2)[(nt * 4 + ks) * 64 + lane], acc[nt], 0, 0, 0);
    }
  }
  {
    const int r0 = m0 + hi * 4;
#pragma unroll
    for (int nt = 0; nt < 8; ++nt) {
      const int col = nt * 16 + row;
      float bb = b2[col];
#pragma unroll
      for (int i = 0; i < 4; ++i) {
        float v = fmaxf(acc[nt][i] + bb, 0.f);
        Hout[(size_t)(r0 + i) * 128 + col] = f2bf(v);
      }
    }
  }
}

extern "C" void kernel_launch(void* const* d_in, const int* in_sizes, int n_in,
                              void* d_out, int out_size, void* d_ws, size_t ws_size,
                              hipStream_t stream) {
  const float* x    = (const float*)d_in[0];
  const int*   ei   = (const int*)d_in[1];
  const int*   batch= (const int*)d_in[2];
  const float* Wp1  = (const float*)d_in[3];
  const float* bp1  = (const float*)d_in[4];
  const float* Wp2  = (const float*)d_in[5];
  const float* bp2  = (const float*)d_in[6];
  const float* W1s  = (const float*)d_in[7];
  const float* b1s  = (const float*)d_in[8];
  const float* W2s  = (const float*)d_in[9];
  const float* b2s  = (const float*)d_in[10];
  const float* eps  = (const float*)d_in[11];

  const int N = in_sizes[0] / 128;
  const int E = in_sizes[1] / 2;
  float* out = (float*)d_out;
  const int nbk = (N + 2047) >> 11;

  char* ws = (char*)d_ws;
  size_t off = 0;
  auto alloc = [&](size_t bytes) -> void* {
    void* p = ws + off;
    off += (bytes + 255) & ~(size_t)255;
    return p;
  };
  ushort* bufA  = (ushort*)alloc((size_t)N * 128 * 2);
  ushort* bufB  = (ushort*)alloc((size_t)N * 128 * 2);
  ushort* Wf    = (ushort*)alloc((size_t)8 * 16384 * 2);
  int* rowbeg   = (int*)alloc((size_t)N * 4);
  int* rowend   = (int*)alloc((size_t)N * 4);
  int* csr      = (int*)alloc((size_t)nbk * ECAP * 4);
  uint2* ebuf   = (uint2*)alloc((size_t)nbk * ECAP * 8);
  int* bcur     = (int*)alloc((size_t)(nbk + 1) * 4);
  (void)ws_size; (void)n_in;

  hipMemsetAsync(out, 0, (size_t)out_size * 4, stream);

  k_prepw<<<64, 256, 0, stream>>>(Wp1, Wp2, W1s, W2s, Wf, bcur, nbk);
  k_part<<<(E + PEPB - 1) / PEPB, 256, 0, stream>>>(ei, ei + E, bcur, ebuf, E);
  k_sort<<<nbk, 1024, 0, stream>>>(ebuf, bcur, rowbeg, rowend, csr, N);

  const int ngrid = (N + 63) / 64;
  k_mlp2<<<ngrid, 256, 0, stream>>>(x, Wf + 0 * 16384, Wf + 1 * 16384, bp1, bp2, bufA, N);

  const int lgrid = (N + 15) / 16;
  ushort* hin = bufA;
  ushort* hout = bufB;
  for (int L = 0; L < 3; ++L) {
    k_layer<<<lgrid, 256, 0, stream>>>(hin, rowbeg, rowend, csr,
                                       Wf + (2 + L) * 16384, Wf + (5 + L) * 16384,
                                       b1s + (size_t)L * 128, b2s + (size_t)L * 128,
                                       eps, L, hout, batch, out, L * 128, N);
    ushort* tmp = hin; hin = hout; hout = tmp;
  }
}